// Round 6
// baseline (423.150 us; speedup 1.0000x reference)
//
#include <hip/hip_runtime.h>
#include <cmath>

#define HIDC 48

// ---------------------------------------------------------------------------
// block-wide mean/var over NPIX values spread across 1024 threads.
// ---------------------------------------------------------------------------
__device__ __forceinline__ void block_meanvar1024(float s, float s2, float* red,
                                                  float cntinv, float& m, float& v)
{
#pragma unroll
    for (int off = 32; off > 0; off >>= 1) {
        s  += __shfl_down(s, off);
        s2 += __shfl_down(s2, off);
    }
    int wid  = threadIdx.x >> 6;   // 0..15
    int lane = threadIdx.x & 63;
    if (lane == 0) { red[wid] = s; red[16 + wid] = s2; }
    __syncthreads();
    if (threadIdx.x == 0) {
        float ts = 0.f, ts2 = 0.f;
#pragma unroll
        for (int i = 0; i < 16; ++i) { ts += red[i]; ts2 += red[16 + i]; }
        red[32] = ts; red[33] = ts2;
    }
    __syncthreads();
    float mean = red[32] * cntinv;
    m = mean;
    v = red[33] * cntinv - mean * mean;
    __syncthreads();
}

// ---------------------------------------------------------------------------
// Pure conv3x3(SAME, zero-pad) + bias.
// 256 threads; each thread computes PXT horizontally-consecutive pixels of
// one row for COG consecutive couts. Tile = ROWS x W.
// Grid: (COUT/COG, H/ROWS, N). Register prefetch of stage s+1's global data
// during stage s compute; double-buffered LDS with ONE barrier per stage.
// ---------------------------------------------------------------------------
template <int H, int W, int ROWS, int COG, int CPS, int PXT>
__global__ __launch_bounds__(256) void conv_tile(
    const float* __restrict__ in,    // (N, 48, H, W)
    const float* __restrict__ wgt,   // (COUT, 48, 3, 3)
    const float* __restrict__ bias,  // (COUT)
    float* __restrict__ out)         // (N, COUT, H, W)
{
    constexpr int NPIX = H * W;
    constexpr int PW   = W + 2;
    constexpr int CHSZ = (ROWS + 2) * PW;
    constexpr int LSZ  = CPS * CHSZ;
    constexpr int TXN  = W / PXT;          // threads per row
    constexpr int NS   = 48 / CPS;
    constexpr int LPT  = (LSZ + 255) / 256;

    static_assert(ROWS * TXN == 256, "block must be 256 threads");

    __shared__ float plane[2][LSZ];

    const int t    = threadIdx.x;
    const int cg   = blockIdx.x;
    const int rt   = blockIdx.y;
    const int n    = blockIdx.z;
    const int COUT = gridDim.x * COG;
    const int co0  = cg * COG;
    const int tx   = t % TXN;
    const int ty   = t / TXN;              // row within tile
    const int x0   = tx * PXT;
    const int r0   = rt * ROWS;

    float acc[COG][PXT];
#pragma unroll
    for (int co = 0; co < COG; ++co)
#pragma unroll
        for (int p = 0; p < PXT; ++p) acc[co][p] = 0.f;

    const float* inb = in + (size_t)n * 48 * NPIX;

    // prefetch stage 0
    float pref[LPT];
#pragma unroll
    for (int k = 0; k < LPT; ++k) {
        int i = t + k * 256;
        float v = 0.f;
        if (i < LSZ) {
            int ch  = i / CHSZ;
            int rem = i % CHSZ;
            int ly  = rem / PW, lx = rem % PW;
            int gy  = r0 + ly - 1, gx = lx - 1;
            if (gy >= 0 && gy < H && gx >= 0 && gx < W)
                v = inb[(size_t)ch * NPIX + gy * W + gx];
        }
        pref[k] = v;
    }

    int buf = 0;
    for (int s = 0; s < NS; ++s) {
        float cur[LPT];
#pragma unroll
        for (int k = 0; k < LPT; ++k) cur[k] = pref[k];
        if (s + 1 < NS) {
            const float* nb = inb + (size_t)(s + 1) * CPS * NPIX;
#pragma unroll
            for (int k = 0; k < LPT; ++k) {
                int i = t + k * 256;
                float v = 0.f;
                if (i < LSZ) {
                    int ch  = i / CHSZ;
                    int rem = i % CHSZ;
                    int ly  = rem / PW, lx = rem % PW;
                    int gy  = r0 + ly - 1, gx = lx - 1;
                    if (gy >= 0 && gy < H && gx >= 0 && gx < W)
                        v = nb[(size_t)ch * NPIX + gy * W + gx];
                }
                pref[k] = v;
            }
        }
#pragma unroll
        for (int k = 0; k < LPT; ++k) {
            int i = t + k * 256;
            if (i < LSZ) plane[buf][i] = cur[k];
        }
        __syncthreads();

#pragma unroll
        for (int c = 0; c < CPS; ++c) {
            const float* P = &plane[buf][c * CHSZ];
            float wv[COG][9];
#pragma unroll
            for (int co = 0; co < COG; ++co)
#pragma unroll
                for (int k = 0; k < 9; ++k)
                    wv[co][k] = wgt[((size_t)(co0 + co) * 48 + s * CPS + c) * 9 + k];
            float vr[3][PXT + 2];
#pragma unroll
            for (int r = 0; r < 3; ++r)
#pragma unroll
                for (int j = 0; j < PXT + 2; ++j)
                    vr[r][j] = P[(ty + r) * PW + x0 + j];
#pragma unroll
            for (int co = 0; co < COG; ++co)
#pragma unroll
                for (int p = 0; p < PXT; ++p) {
                    float s0 = vr[0][p]     * wv[co][0] + vr[0][p + 1] * wv[co][1]
                             + vr[0][p + 2] * wv[co][2] + vr[1][p]     * wv[co][3]
                             + vr[1][p + 1] * wv[co][4] + vr[1][p + 2] * wv[co][5]
                             + vr[2][p]     * wv[co][6] + vr[2][p + 1] * wv[co][7]
                             + vr[2][p + 2] * wv[co][8];
                    acc[co][p] += s0;
                }
        }
        buf ^= 1;
        // single barrier per stage: stage s+1 writes the buffer read at s-1;
        // all reads of that buffer preceded this thread's barrier arrival.
    }

#pragma unroll
    for (int co = 0; co < COG; ++co) {
        const float bv = bias[co0 + co];
        float* op = out + (((size_t)n * COUT + co0 + co) * H + r0 + ty) * W + x0;
        if (PXT == 2) {
            float2 o2 = make_float2(acc[co][0] + bv, acc[co][PXT - 1] + bv);
            *(float2*)op = o2;
        } else {
#pragma unroll
            for (int p = 0; p < PXT; ++p) op[p] = acc[co][p] + bv;
        }
    }
}

// ---------------------------------------------------------------------------
// Per-plane epilogue: inorm, prelu [, inorm, +residual].
//   MODE 0: inorm, prelu, inorm, +res   MODE 1: inorm, prelu
// ---------------------------------------------------------------------------
template <int NPIX, int MODE>
__global__ __launch_bounds__(1024) void norm_block(
    const float* __restrict__ conv,
    const float* __restrict__ res,
    const float* __restrict__ aptr,
    float* __restrict__ out)
{
    constexpr int TY = NPIX / 1024;
    __shared__ float red[34];
    const int t  = threadIdx.x;
    const int co = blockIdx.x;
    const int n  = blockIdx.y;
    const size_t base = ((size_t)n * 48 + co) * NPIX;
    constexpr float cntinv = 1.f / (float)NPIX;

    float acc[TY];
#pragma unroll
    for (int r = 0; r < TY; ++r) acc[r] = conv[base + t + r * 1024];

    {
        float s = 0.f, s2 = 0.f;
#pragma unroll
        for (int r = 0; r < TY; ++r) { s += acc[r]; s2 += acc[r] * acc[r]; }
        float m, v;
        block_meanvar1024(s, s2, red, cntinv, m, v);
        float rr = rsqrtf(v + 1e-5f);
#pragma unroll
        for (int r = 0; r < TY; ++r) acc[r] = (acc[r] - m) * rr;
    }

    const float a = aptr[0];
#pragma unroll
    for (int r = 0; r < TY; ++r) acc[r] = acc[r] >= 0.f ? acc[r] : a * acc[r];

    if (MODE == 0) {
        float s = 0.f, s2 = 0.f;
#pragma unroll
        for (int r = 0; r < TY; ++r) { s += acc[r]; s2 += acc[r] * acc[r]; }
        float m, v;
        block_meanvar1024(s, s2, red, cntinv, m, v);
        float rr = rsqrtf(v + 1e-5f);
#pragma unroll
        for (int r = 0; r < TY; ++r)
            acc[r] = (acc[r] - m) * rr + res[base + t + r * 1024];
    }

#pragma unroll
    for (int r = 0; r < TY; ++r) out[base + t + r * 1024] = acc[r];
}

// ---------------------------------------------------------------------------
__global__ __launch_bounds__(256) void downsample4(const float* __restrict__ xin,
                                                   float* __restrict__ o)
{
    int idx = blockIdx.x * 256 + threadIdx.x;        // 786432
    int j = idx & 63;
    int i = (idx >> 6) & 63;
    int nc = idx >> 12;
    o[idx] = xin[((size_t)nc * 256 + i * 4) * 256 + j * 4];
}

// ---------------------------------------------------------------------------
__global__ __launch_bounds__(256) void maxpool2k(const float* __restrict__ a,
                                                 float* __restrict__ o)
{
    int idx = blockIdx.x * 256 + threadIdx.x;        // 196608
    int j = idx & 31;
    int i = (idx >> 5) & 31;
    int nc = idx >> 10;
    const float* p = a + ((size_t)nc * 64 + i * 2) * 64 + j * 2;
    o[idx] = fmaxf(fmaxf(p[0], p[1]), fmaxf(p[64], p[65]));
}

// ---------------------------------------------------------------------------
// Precompute the softmaxed, bilinearly-upsampled kernel field:
// kvf[n][h][w][9]  (4,256,256,9) fp32. Grid (256 rows, 4 n), 256 threads.
// LDS transpose stage so global writes are fully coalesced and LDS reads
// are lane-consecutive (conflict-free).
// ---------------------------------------------------------------------------
__global__ __launch_bounds__(256) void kv_field(const float* __restrict__ sk,
                                                float* __restrict__ kvf)
{
    __shared__ float skr[9][2][32];
    __shared__ float kvs[256 * 9];     // [w][p] flat
    const int h = blockIdx.x;
    const int n = blockIdx.y;
    const int t = threadIdx.x;

    float fs = (float)h * 31.0f / 255.0f;
    int r0 = (int)fs;
    float fh = fs - (float)r0;
    int r1 = min(r0 + 1, 31);

    for (int i = t; i < 576; i += 256) {
        int p = i >> 6, rsel = (i >> 5) & 1, c = i & 31;
        int rr = rsel ? r1 : r0;
        skr[p][rsel][c] = sk[((n * 9 + p) * 32 + rr) * 32 + c];
    }
    __syncthreads();

    {
        float fcs = (float)t * 31.0f / 255.0f;
        int c0 = (int)fcs;
        float fx = fcs - (float)c0;
        int c1 = min(c0 + 1, 31);
        float kv[9];
        float mx = -1e30f;
#pragma unroll
        for (int p = 0; p < 9; ++p) {
            float v0 = skr[p][0][c0] * (1.f - fx) + skr[p][0][c1] * fx;
            float v1 = skr[p][1][c0] * (1.f - fx) + skr[p][1][c1] * fx;
            float v  = v0 * (1.f - fh) + v1 * fh;
            kv[p] = v;
            mx = fmaxf(mx, v);
        }
        float ss = 0.f;
#pragma unroll
        for (int p = 0; p < 9; ++p) { kv[p] = __expf(kv[p] - mx); ss += kv[p]; }
        float inv = 1.f / ss;
#pragma unroll
        for (int p = 0; p < 9; ++p) kvs[t * 9 + p] = kv[p] * inv;
    }
    __syncthreads();

    float* ob = kvf + ((size_t)(n * 256 + h) * 256) * 9;
#pragma unroll
    for (int i = 0; i < 9; ++i) {
        int j = t + i * 256;
        ob[j] = kvs[j];     // LDS read lane-consecutive, global write coalesced
    }
}

// ---------------------------------------------------------------------------
// Apply: 3x3 reflect-padded per-pixel kernel from kvf to x.
// Grid (16, 256): x = n*4+cg (12 channels each), y = row h. No LDS/barrier.
// Thread t: pixel quad w4=(t&63)*4, channels cg*12+(t>>6)*3+{0..2}.
// kv: 9 aligned dwordx4 loads; x: 27 loads, all hoisted before compute.
// ---------------------------------------------------------------------------
__global__ __launch_bounds__(256) void apply2(const float* __restrict__ x,
                                              const float* __restrict__ kvf,
                                              float* __restrict__ out)
{
    const int bx = blockIdx.x;
    const int n  = bx >> 2;
    const int cg = bx & 3;
    const int h  = blockIdx.y;
    const int t  = threadIdx.x;

    const int wq = t & 63;
    const int cl = t >> 6;
    const int w4 = wq * 4;

    // --- kv for 4 pixels: 36 consecutive floats, 16B-aligned ---
    float kvr[36];
    {
        const float* kp = kvf + ((size_t)(n * 256 + h) * 256 + w4) * 9;
#pragma unroll
        for (int q = 0; q < 9; ++q)
            *(float4*)&kvr[q * 4] = *(const float4*)(kp + q * 4);
    }

    const int hm  = (h == 0) ? 1 : h - 1;
    const int hp  = (h == 255) ? 254 : h + 1;
    const int xle = (w4 == 0) ? 1 : w4 - 1;
    const int xre = (w4 == 252) ? 254 : w4 + 4;

    const int c0ch = cg * 12 + cl * 3;
    const float* xb = x + ((size_t)n * HIDC + c0ch) * 65536;
    float* ob = out + ((size_t)n * HIDC + c0ch) * 65536;

    // --- hoist all 27 x loads ---
    float vm[3][6], vc[3][6], vp[3][6];
#pragma unroll
    for (int c = 0; c < 3; ++c) {
        const float* xp = xb + (size_t)c * 65536;
        const float* rm = xp + hm * 256;
        const float* rc = xp + h * 256;
        const float* rp = xp + hp * 256;
        float4 fm = *(const float4*)(rm + w4);
        float4 fc = *(const float4*)(rc + w4);
        float4 fp = *(const float4*)(rp + w4);
        vm[c][0] = rm[xle]; vm[c][1] = fm.x; vm[c][2] = fm.y; vm[c][3] = fm.z; vm[c][4] = fm.w; vm[c][5] = rm[xre];
        vc[c][0] = rc[xle]; vc[c][1] = fc.x; vc[c][2] = fc.y; vc[c][3] = fc.z; vc[c][4] = fc.w; vc[c][5] = rc[xre];
        vp[c][0] = rp[xle]; vp[c][1] = fp.x; vp[c][2] = fp.y; vp[c][3] = fp.z; vp[c][4] = fp.w; vp[c][5] = rp[xre];
    }

#pragma unroll
    for (int c = 0; c < 3; ++c) {
        float4 o;
        float* op = &o.x;
#pragma unroll
        for (int j = 0; j < 4; ++j) {
            const float* kv = &kvr[j * 9];
            op[j] = kv[0] * vm[c][j] + kv[1] * vm[c][j + 1] + kv[2] * vm[c][j + 2]
                  + kv[3] * vc[c][j] + kv[4] * vc[c][j + 1] + kv[5] * vc[c][j + 2]
                  + kv[6] * vp[c][j] + kv[7] * vp[c][j + 1] + kv[8] * vp[c][j + 2];
        }
        *(float4*)(ob + (size_t)c * 65536 + h * 256 + w4) = o;
    }
}

extern "C" void kernel_launch(void* const* d_in, const int* in_sizes, int n_in,
                              void* d_out, int out_size, void* d_ws, size_t ws_size,
                              hipStream_t stream)
{
    const float* x       = (const float*)d_in[0];
    const float* x_      = (const float*)d_in[1];
    const float* pre1_w  = (const float*)d_in[2];
    const float* pre1_b  = (const float*)d_in[3];
    const float* pre1_a  = (const float*)d_in[4];
    const float* pre2_w  = (const float*)d_in[5];
    const float* pre2_b  = (const float*)d_in[6];
    const float* pre2_a  = (const float*)d_in[7];
    const float* prek_w1 = (const float*)d_in[8];
    const float* prek_b1 = (const float*)d_in[9];
    const float* prek_a  = (const float*)d_in[10];
    const float* prek_w2 = (const float*)d_in[11];
    const float* prek_b2 = (const float*)d_in[12];
    float* out = (float*)d_out;

    float* A   = (float*)d_ws;          // (4,48,64,64) = 786432
    float* B   = A + 786432;            // (4,48,64,64)
    float* RAW = B + 786432;            // (4,48,64,64) raw conv out
    float* KVF = RAW + 786432;          // (4,256,256,9) = 2359296
    float* C   = A;                     // (4,48,32,32) = 196608  (A dead by then)
    float* D   = A + 196608;            // (4,48,32,32)
    float* R2  = A + 393216;            // (4,48,32,32) raw conv out
    float* SK  = A + 589824;            // (4,9,32,32)

    const int W1 = 48 * 48 * 9;

    downsample4<<<3072, 256, 0, stream>>>(x_, A);

    // ---- 3 basic blocks @ 64x64 : CPS=4 (12 stages), 768 blocks ----
    conv_tile<64, 64, 8, 2, 4, 2><<<dim3(24, 8, 4), 256, 0, stream>>>(A, pre1_w, pre1_b, RAW);
    norm_block<4096, 0><<<dim3(48, 4), 1024, 0, stream>>>(RAW, A, pre1_a, B);
    conv_tile<64, 64, 8, 2, 4, 2><<<dim3(24, 8, 4), 256, 0, stream>>>(B, pre1_w + W1, pre1_b + 48, RAW);
    norm_block<4096, 0><<<dim3(48, 4), 1024, 0, stream>>>(RAW, B, pre1_a + 1, A);
    conv_tile<64, 64, 8, 2, 4, 2><<<dim3(24, 8, 4), 256, 0, stream>>>(A, pre1_w + 2 * W1, pre1_b + 96, RAW);
    norm_block<4096, 0><<<dim3(48, 4), 1024, 0, stream>>>(RAW, A, pre1_a + 2, B);

    maxpool2k<<<768, 256, 0, stream>>>(B, C);

    // ---- 3 basic blocks @ 32x32 : CPS=8 (6 stages), 384 blocks ----
    conv_tile<32, 32, 8, 2, 8, 1><<<dim3(24, 4, 4), 256, 0, stream>>>(C, pre2_w, pre2_b, R2);
    norm_block<1024, 0><<<dim3(48, 4), 1024, 0, stream>>>(R2, C, pre2_a, D);
    conv_tile<32, 32, 8, 2, 8, 1><<<dim3(24, 4, 4), 256, 0, stream>>>(D, pre2_w + W1, pre2_b + 48, R2);
    norm_block<1024, 0><<<dim3(48, 4), 1024, 0, stream>>>(R2, D, pre2_a + 1, C);
    conv_tile<32, 32, 8, 2, 8, 1><<<dim3(24, 4, 4), 256, 0, stream>>>(C, pre2_w + 2 * W1, pre2_b + 96, R2);
    norm_block<1024, 0><<<dim3(48, 4), 1024, 0, stream>>>(R2, C, pre2_a + 2, D);

    // ---- kernel-prediction heads ----
    conv_tile<32, 32, 8, 2, 8, 1><<<dim3(24, 4, 4), 256, 0, stream>>>(D, prek_w1, prek_b1, R2);
    norm_block<1024, 1><<<dim3(48, 4), 1024, 0, stream>>>(R2, nullptr, prek_a, C);
    conv_tile<32, 32, 8, 3, 8, 1><<<dim3(3, 4, 4), 256, 0, stream>>>(C, prek_w2, prek_b2, SK);

    kv_field<<<dim3(256, 4), 256, 0, stream>>>(SK, KVF);
    apply2<<<dim3(16, 256), 256, 0, stream>>>(x, KVF, out);
}

// Round 7
// 402.418 us; speedup vs baseline: 1.0515x; 1.0515x over previous
//
#include <hip/hip_runtime.h>
#include <cmath>

#define HIDC 48

// ---------------------------------------------------------------------------
// block-wide mean/var over NPIX values spread across 1024 threads.
// ---------------------------------------------------------------------------
__device__ __forceinline__ void block_meanvar1024(float s, float s2, float* red,
                                                  float cntinv, float& m, float& v)
{
#pragma unroll
    for (int off = 32; off > 0; off >>= 1) {
        s  += __shfl_down(s, off);
        s2 += __shfl_down(s2, off);
    }
    int wid  = threadIdx.x >> 6;   // 0..15
    int lane = threadIdx.x & 63;
    if (lane == 0) { red[wid] = s; red[16 + wid] = s2; }
    __syncthreads();
    if (threadIdx.x == 0) {
        float ts = 0.f, ts2 = 0.f;
#pragma unroll
        for (int i = 0; i < 16; ++i) { ts += red[i]; ts2 += red[16 + i]; }
        red[32] = ts; red[33] = ts2;
    }
    __syncthreads();
    float mean = red[32] * cntinv;
    m = mean;
    v = red[33] * cntinv - mean * mean;
    __syncthreads();
}

// ---------------------------------------------------------------------------
// Pure conv3x3(SAME, zero-pad) + bias.
// 256 threads; each thread computes PXT horizontally-consecutive pixels of
// one row for COG consecutive couts. Tile = ROWS x W.
// Grid: (COUT/COG, H/ROWS, N). Register prefetch of stage s+1's global data
// during stage s compute; double-buffered LDS with ONE barrier per stage.
// ---------------------------------------------------------------------------
template <int H, int W, int ROWS, int COG, int CPS, int PXT>
__global__ __launch_bounds__(256) void conv_tile(
    const float* __restrict__ in,    // (N, 48, H, W)
    const float* __restrict__ wgt,   // (COUT, 48, 3, 3)
    const float* __restrict__ bias,  // (COUT)
    float* __restrict__ out)         // (N, COUT, H, W)
{
    constexpr int NPIX = H * W;
    constexpr int PW   = W + 2;
    constexpr int CHSZ = (ROWS + 2) * PW;
    constexpr int LSZ  = CPS * CHSZ;
    constexpr int TXN  = W / PXT;          // threads per row
    constexpr int NS   = 48 / CPS;
    constexpr int LPT  = (LSZ + 255) / 256;

    static_assert(ROWS * TXN == 256, "block must be 256 threads");

    __shared__ float plane[2][LSZ];

    const int t    = threadIdx.x;
    const int cg   = blockIdx.x;
    const int rt   = blockIdx.y;
    const int n    = blockIdx.z;
    const int COUT = gridDim.x * COG;
    const int co0  = cg * COG;
    const int tx   = t % TXN;
    const int ty   = t / TXN;              // row within tile
    const int x0   = tx * PXT;
    const int r0   = rt * ROWS;

    float acc[COG][PXT];
#pragma unroll
    for (int co = 0; co < COG; ++co)
#pragma unroll
        for (int p = 0; p < PXT; ++p) acc[co][p] = 0.f;

    const float* inb = in + (size_t)n * 48 * NPIX;

    // prefetch stage 0
    float pref[LPT];
#pragma unroll
    for (int k = 0; k < LPT; ++k) {
        int i = t + k * 256;
        float v = 0.f;
        if (i < LSZ) {
            int ch  = i / CHSZ;
            int rem = i % CHSZ;
            int ly  = rem / PW, lx = rem % PW;
            int gy  = r0 + ly - 1, gx = lx - 1;
            if (gy >= 0 && gy < H && gx >= 0 && gx < W)
                v = inb[(size_t)ch * NPIX + gy * W + gx];
        }
        pref[k] = v;
    }

    int buf = 0;
    for (int s = 0; s < NS; ++s) {
        float cur[LPT];
#pragma unroll
        for (int k = 0; k < LPT; ++k) cur[k] = pref[k];
        if (s + 1 < NS) {
            const float* nb = inb + (size_t)(s + 1) * CPS * NPIX;
#pragma unroll
            for (int k = 0; k < LPT; ++k) {
                int i = t + k * 256;
                float v = 0.f;
                if (i < LSZ) {
                    int ch  = i / CHSZ;
                    int rem = i % CHSZ;
                    int ly  = rem / PW, lx = rem % PW;
                    int gy  = r0 + ly - 1, gx = lx - 1;
                    if (gy >= 0 && gy < H && gx >= 0 && gx < W)
                        v = nb[(size_t)ch * NPIX + gy * W + gx];
                }
                pref[k] = v;
            }
        }
#pragma unroll
        for (int k = 0; k < LPT; ++k) {
            int i = t + k * 256;
            if (i < LSZ) plane[buf][i] = cur[k];
        }
        __syncthreads();

#pragma unroll
        for (int c = 0; c < CPS; ++c) {
            const float* P = &plane[buf][c * CHSZ];
            float wv[COG][9];
#pragma unroll
            for (int co = 0; co < COG; ++co)
#pragma unroll
                for (int k = 0; k < 9; ++k)
                    wv[co][k] = wgt[((size_t)(co0 + co) * 48 + s * CPS + c) * 9 + k];
            float vr[3][PXT + 2];
#pragma unroll
            for (int r = 0; r < 3; ++r)
#pragma unroll
                for (int j = 0; j < PXT + 2; ++j)
                    vr[r][j] = P[(ty + r) * PW + x0 + j];
#pragma unroll
            for (int co = 0; co < COG; ++co)
#pragma unroll
                for (int p = 0; p < PXT; ++p) {
                    float s0 = vr[0][p]     * wv[co][0] + vr[0][p + 1] * wv[co][1]
                             + vr[0][p + 2] * wv[co][2] + vr[1][p]     * wv[co][3]
                             + vr[1][p + 1] * wv[co][4] + vr[1][p + 2] * wv[co][5]
                             + vr[2][p]     * wv[co][6] + vr[2][p + 1] * wv[co][7]
                             + vr[2][p + 2] * wv[co][8];
                    acc[co][p] += s0;
                }
        }
        buf ^= 1;
        // single barrier per stage: stage s+1 writes the buffer read at s-1;
        // all reads of that buffer preceded this thread's barrier arrival.
    }

#pragma unroll
    for (int co = 0; co < COG; ++co) {
        const float bv = bias[co0 + co];
        float* op = out + (((size_t)n * COUT + co0 + co) * H + r0 + ty) * W + x0;
        if (PXT == 2) {
            float2 o2 = make_float2(acc[co][0] + bv, acc[co][PXT - 1] + bv);
            *(float2*)op = o2;
        } else {
#pragma unroll
            for (int p = 0; p < PXT; ++p) op[p] = acc[co][p] + bv;
        }
    }
}

// ---------------------------------------------------------------------------
// Per-plane epilogue: inorm, prelu [, inorm, +residual].
//   MODE 0: inorm, prelu, inorm, +res   MODE 1: inorm, prelu
// ---------------------------------------------------------------------------
template <int NPIX, int MODE>
__global__ __launch_bounds__(1024) void norm_block(
    const float* __restrict__ conv,
    const float* __restrict__ res,
    const float* __restrict__ aptr,
    float* __restrict__ out)
{
    constexpr int TY = NPIX / 1024;
    __shared__ float red[34];
    const int t  = threadIdx.x;
    const int co = blockIdx.x;
    const int n  = blockIdx.y;
    const size_t base = ((size_t)n * 48 + co) * NPIX;
    constexpr float cntinv = 1.f / (float)NPIX;

    float acc[TY];
#pragma unroll
    for (int r = 0; r < TY; ++r) acc[r] = conv[base + t + r * 1024];

    {
        float s = 0.f, s2 = 0.f;
#pragma unroll
        for (int r = 0; r < TY; ++r) { s += acc[r]; s2 += acc[r] * acc[r]; }
        float m, v;
        block_meanvar1024(s, s2, red, cntinv, m, v);
        float rr = rsqrtf(v + 1e-5f);
#pragma unroll
        for (int r = 0; r < TY; ++r) acc[r] = (acc[r] - m) * rr;
    }

    const float a = aptr[0];
#pragma unroll
    for (int r = 0; r < TY; ++r) acc[r] = acc[r] >= 0.f ? acc[r] : a * acc[r];

    if (MODE == 0) {
        float s = 0.f, s2 = 0.f;
#pragma unroll
        for (int r = 0; r < TY; ++r) { s += acc[r]; s2 += acc[r] * acc[r]; }
        float m, v;
        block_meanvar1024(s, s2, red, cntinv, m, v);
        float rr = rsqrtf(v + 1e-5f);
#pragma unroll
        for (int r = 0; r < TY; ++r)
            acc[r] = (acc[r] - m) * rr + res[base + t + r * 1024];
    }

#pragma unroll
    for (int r = 0; r < TY; ++r) out[base + t + r * 1024] = acc[r];
}

// ---------------------------------------------------------------------------
__global__ __launch_bounds__(256) void downsample4(const float* __restrict__ xin,
                                                   float* __restrict__ o)
{
    int idx = blockIdx.x * 256 + threadIdx.x;        // 786432
    int j = idx & 63;
    int i = (idx >> 6) & 63;
    int nc = idx >> 12;
    o[idx] = xin[((size_t)nc * 256 + i * 4) * 256 + j * 4];
}

// ---------------------------------------------------------------------------
__global__ __launch_bounds__(256) void maxpool2k(const float* __restrict__ a,
                                                 float* __restrict__ o)
{
    int idx = blockIdx.x * 256 + threadIdx.x;        // 196608
    int j = idx & 31;
    int i = (idx >> 5) & 31;
    int nc = idx >> 10;
    const float* p = a + ((size_t)nc * 64 + i * 2) * 64 + j * 2;
    o[idx] = fmaxf(fmaxf(p[0], p[1]), fmaxf(p[64], p[65]));
}

// ---------------------------------------------------------------------------
// Precompute the softmaxed, bilinearly-upsampled kernel field:
// kvf[n][h][w][9]  (4,256,256,9) fp32. Grid (256 rows, 4 n), 256 threads.
// ---------------------------------------------------------------------------
__global__ __launch_bounds__(256) void kv_field(const float* __restrict__ sk,
                                                float* __restrict__ kvf)
{
    __shared__ float skr[9][2][32];
    __shared__ float kvs[256 * 9];     // [w][p] flat
    const int h = blockIdx.x;
    const int n = blockIdx.y;
    const int t = threadIdx.x;

    float fs = (float)h * 31.0f / 255.0f;
    int r0 = (int)fs;
    float fh = fs - (float)r0;
    int r1 = min(r0 + 1, 31);

    for (int i = t; i < 576; i += 256) {
        int p = i >> 6, rsel = (i >> 5) & 1, c = i & 31;
        int rr = rsel ? r1 : r0;
        skr[p][rsel][c] = sk[((n * 9 + p) * 32 + rr) * 32 + c];
    }
    __syncthreads();

    {
        float fcs = (float)t * 31.0f / 255.0f;
        int c0 = (int)fcs;
        float fx = fcs - (float)c0;
        int c1 = min(c0 + 1, 31);
        float kv[9];
        float mx = -1e30f;
#pragma unroll
        for (int p = 0; p < 9; ++p) {
            float v0 = skr[p][0][c0] * (1.f - fx) + skr[p][0][c1] * fx;
            float v1 = skr[p][1][c0] * (1.f - fx) + skr[p][1][c1] * fx;
            float v  = v0 * (1.f - fh) + v1 * fh;
            kv[p] = v;
            mx = fmaxf(mx, v);
        }
        float ss = 0.f;
#pragma unroll
        for (int p = 0; p < 9; ++p) { kv[p] = __expf(kv[p] - mx); ss += kv[p]; }
        float inv = 1.f / ss;
#pragma unroll
        for (int p = 0; p < 9; ++p) kvs[t * 9 + p] = kv[p] * inv;
    }
    __syncthreads();

    float* ob = kvf + ((size_t)(n * 256 + h) * 256) * 9;
#pragma unroll
    for (int i = 0; i < 9; ++i) {
        int j = t + i * 256;
        ob[j] = kvs[j];
    }
}

// ---------------------------------------------------------------------------
// Apply: 3x3 reflect-padded per-pixel kernel from kvf to x.
// ONE block per (n, h): grid (256, 4), 256 threads. Wave lane == pixel quad
// (wq = t&63, w4 = wq*4); cl = t>>6 picks 12 channels. kv for a quad is
// loaded from kvf by all 4 cl-threads of the same block -> same-CU L1 hits,
// kvf HBM-fetched once per (n,h). Horizontal neighbors come from wave
// shuffles (lane +/- 1) instead of extra scalar loads; reflect at lanes 0/63.
// Channels processed in 4-chunks to bound VGPRs.
// ---------------------------------------------------------------------------
__global__ __launch_bounds__(256) void apply3(const float* __restrict__ x,
                                              const float* __restrict__ kvf,
                                              float* __restrict__ out)
{
    const int h  = blockIdx.x;
    const int n  = blockIdx.y;
    const int t  = threadIdx.x;
    const int wq = t & 63;
    const int cl = t >> 6;
    const int w4 = wq * 4;

    // kv for this quad: 36 consecutive floats (16B-aligned)
    float kvr[36];
    {
        const float* kp = kvf + ((size_t)(n * 256 + h) * 256 + w4) * 9;
#pragma unroll
        for (int q = 0; q < 9; ++q)
            *(float4*)&kvr[q * 4] = *(const float4*)(kp + q * 4);
    }

    const int hm = (h == 0) ? 1 : h - 1;
    const int hp = (h == 255) ? 254 : h + 1;

    const float* xb = x + ((size_t)n * HIDC + cl * 12) * 65536;
    float* ob = out + ((size_t)n * HIDC + cl * 12) * 65536;

    for (int cc = 0; cc < 12; cc += 4) {
        float4 fm[4], fc[4], fp[4];
#pragma unroll
        for (int k = 0; k < 4; ++k) {
            const float* xp = xb + (size_t)(cc + k) * 65536;
            fm[k] = *(const float4*)(xp + hm * 256 + w4);
            fc[k] = *(const float4*)(xp + h  * 256 + w4);
            fp[k] = *(const float4*)(xp + hp * 256 + w4);
        }
#pragma unroll
        for (int k = 0; k < 4; ++k) {
            // horizontal neighbors via wave shuffle (lane == quad)
            float lm = __shfl_up(fm[k].w, 1);  if (wq == 0)  lm = fm[k].y;
            float lc = __shfl_up(fc[k].w, 1);  if (wq == 0)  lc = fc[k].y;
            float lp = __shfl_up(fp[k].w, 1);  if (wq == 0)  lp = fp[k].y;
            float rm = __shfl_down(fm[k].x, 1); if (wq == 63) rm = fm[k].z;
            float rc = __shfl_down(fc[k].x, 1); if (wq == 63) rc = fc[k].z;
            float rp = __shfl_down(fp[k].x, 1); if (wq == 63) rp = fp[k].z;

            float vm[6] = { lm, fm[k].x, fm[k].y, fm[k].z, fm[k].w, rm };
            float vc[6] = { lc, fc[k].x, fc[k].y, fc[k].z, fc[k].w, rc };
            float vp[6] = { lp, fp[k].x, fp[k].y, fp[k].z, fp[k].w, rp };

            float4 o;
            float* op = &o.x;
#pragma unroll
            for (int j = 0; j < 4; ++j) {
                const float* kv = &kvr[j * 9];
                op[j] = kv[0] * vm[j] + kv[1] * vm[j + 1] + kv[2] * vm[j + 2]
                      + kv[3] * vc[j] + kv[4] * vc[j + 1] + kv[5] * vc[j + 2]
                      + kv[6] * vp[j] + kv[7] * vp[j + 1] + kv[8] * vp[j + 2];
            }
            *(float4*)(ob + (size_t)(cc + k) * 65536 + h * 256 + w4) = o;
        }
    }
}

extern "C" void kernel_launch(void* const* d_in, const int* in_sizes, int n_in,
                              void* d_out, int out_size, void* d_ws, size_t ws_size,
                              hipStream_t stream)
{
    const float* x       = (const float*)d_in[0];
    const float* x_      = (const float*)d_in[1];
    const float* pre1_w  = (const float*)d_in[2];
    const float* pre1_b  = (const float*)d_in[3];
    const float* pre1_a  = (const float*)d_in[4];
    const float* pre2_w  = (const float*)d_in[5];
    const float* pre2_b  = (const float*)d_in[6];
    const float* pre2_a  = (const float*)d_in[7];
    const float* prek_w1 = (const float*)d_in[8];
    const float* prek_b1 = (const float*)d_in[9];
    const float* prek_a  = (const float*)d_in[10];
    const float* prek_w2 = (const float*)d_in[11];
    const float* prek_b2 = (const float*)d_in[12];
    float* out = (float*)d_out;

    float* A   = (float*)d_ws;          // (4,48,64,64) = 786432
    float* B   = A + 786432;            // (4,48,64,64)
    float* RAW = B + 786432;            // (4,48,64,64) raw conv out
    float* KVF = RAW + 786432;          // (4,256,256,9) = 2359296
    float* C   = A;                     // (4,48,32,32) = 196608  (A dead by then)
    float* D   = A + 196608;            // (4,48,32,32)
    float* R2  = A + 393216;            // (4,48,32,32) raw conv out
    float* SK  = A + 589824;            // (4,9,32,32)

    const int W1 = 48 * 48 * 9;

    downsample4<<<3072, 256, 0, stream>>>(x_, A);

    // ---- 3 basic blocks @ 64x64 : CPS=2, 768 blocks ----
    conv_tile<64, 64, 8, 2, 2, 2><<<dim3(24, 8, 4), 256, 0, stream>>>(A, pre1_w, pre1_b, RAW);
    norm_block<4096, 0><<<dim3(48, 4), 1024, 0, stream>>>(RAW, A, pre1_a, B);
    conv_tile<64, 64, 8, 2, 2, 2><<<dim3(24, 8, 4), 256, 0, stream>>>(B, pre1_w + W1, pre1_b + 48, RAW);
    norm_block<4096, 0><<<dim3(48, 4), 1024, 0, stream>>>(RAW, B, pre1_a + 1, A);
    conv_tile<64, 64, 8, 2, 2, 2><<<dim3(24, 8, 4), 256, 0, stream>>>(A, pre1_w + 2 * W1, pre1_b + 96, RAW);
    norm_block<4096, 0><<<dim3(48, 4), 1024, 0, stream>>>(RAW, A, pre1_a + 2, B);

    maxpool2k<<<768, 256, 0, stream>>>(B, C);

    // ---- 3 basic blocks @ 32x32 : CPS=4, 384 blocks ----
    conv_tile<32, 32, 8, 2, 4, 1><<<dim3(24, 4, 4), 256, 0, stream>>>(C, pre2_w, pre2_b, R2);
    norm_block<1024, 0><<<dim3(48, 4), 1024, 0, stream>>>(R2, C, pre2_a, D);
    conv_tile<32, 32, 8, 2, 4, 1><<<dim3(24, 4, 4), 256, 0, stream>>>(D, pre2_w + W1, pre2_b + 48, R2);
    norm_block<1024, 0><<<dim3(48, 4), 1024, 0, stream>>>(R2, D, pre2_a + 1, C);
    conv_tile<32, 32, 8, 2, 4, 1><<<dim3(24, 4, 4), 256, 0, stream>>>(C, pre2_w + 2 * W1, pre2_b + 96, R2);
    norm_block<1024, 0><<<dim3(48, 4), 1024, 0, stream>>>(R2, C, pre2_a + 2, D);

    // ---- kernel-prediction heads ----
    conv_tile<32, 32, 8, 2, 4, 1><<<dim3(24, 4, 4), 256, 0, stream>>>(D, prek_w1, prek_b1, R2);
    norm_block<1024, 1><<<dim3(48, 4), 1024, 0, stream>>>(R2, nullptr, prek_a, C);
    conv_tile<32, 32, 8, 3, 4, 1><<<dim3(3, 4, 4), 256, 0, stream>>>(C, prek_w2, prek_b2, SK);

    kv_field<<<dim3(256, 4), 256, 0, stream>>>(SK, KVF);
    apply3<<<dim3(256, 4), 256, 0, stream>>>(x, KVF, out);
}